// Round 5
// baseline (86.598 us; speedup 1.0000x reference)
//
#include <hip/hip_runtime.h>
#include <math.h>

#define NEG_INF_F (-9000000000000000.0f)
#define ALPHA_F 0.2f

static constexpr int D = 64;
static constexpr int M = 40;

using f32x4 = __attribute__((ext_vector_type(4))) float;

// ---------------------------------------------------------------------------
// Single fused kernel: one wave per row n; entity row in registers (10x f32x4,
// nontemporal). wa1/wa2 computed redundantly PER WAVE (no barrier, no second
// kernel): lane d computes wa1[d], wa2[d] from L1-hot W, then an 8-shuffle
// transpose delivers the f32x4 chunks each lane needs.
// Entity loads are issued FIRST so the HBM stream starts immediately; the
// W-dot's waitcnt drain only delays this wave's VALU work (hidden by TLP).
// Lane layout: q = lane&15 (d-chunk q*4..q*4+3), grp = lane>>4.
// v[i] holds ent[n, m = i*4+grp, d = q*4 .. q*4+3].
// ---------------------------------------------------------------------------
__launch_bounds__(256)
__global__ void kgat_fused(const float* __restrict__ item,
                           const float* __restrict__ ent,
                           const int* __restrict__ adj,
                           const float* __restrict__ W,
                           const float* __restrict__ a,
                           float* __restrict__ out,
                           int N) {
    __shared__ float lds_e[4][M];   // 160 B per wave: e[m] scatter buffer

    const int wave = threadIdx.x >> 6;
    const int lane = threadIdx.x & 63;
    int n = blockIdx.x * 4 + wave;
    const bool valid = (n < N);
    if (!valid) n = N - 1;          // clamp loads; store is guarded

    float* my_e = lds_e[wave];
    const int q   = lane & 15;
    const int grp = lane >> 4;

    const float* row = ent + (size_t)n * (M * D);

    // ---- HBM streaming loads first (nontemporal: read-once) ----
    f32x4 v[10];
#pragma unroll
    for (int i = 0; i < 10; ++i)
        v[i] = __builtin_nontemporal_load(
                   reinterpret_cast<const f32x4*>(row + i * 256 + lane * 4));
    const f32x4 itv = *reinterpret_cast<const f32x4*>(item + (size_t)n * D + q * 4);
    const int   am  = (lane < M) ? adj[(size_t)n * M + lane] : 0;

    // ---- per-wave wa compute: lane d -> wa1[d], wa2[d] ----
    const float* wrow = W + lane * D;
    float acc1 = 0.f, acc2 = 0.f;
#pragma unroll 4
    for (int c = 0; c < 16; ++c) {
        const f32x4 wv  = *reinterpret_cast<const f32x4*>(wrow + c * 4);
        const f32x4 a1v = *reinterpret_cast<const f32x4*>(a + c * 4);      // uniform -> s_load
        const f32x4 a2v = *reinterpret_cast<const f32x4*>(a + D + c * 4);  // uniform -> s_load
        acc1 += wv[0] * a1v[0] + wv[1] * a1v[1] + wv[2] * a1v[2] + wv[3] * a1v[3];
        acc2 += wv[0] * a2v[0] + wv[1] * a2v[1] + wv[2] * a2v[2] + wv[3] * a2v[3];
    }
    // transpose: lane needs wa1[q*4+j], wa2[q*4+j], j=0..3
    f32x4 wa1v, wa2v;
#pragma unroll
    for (int j = 0; j < 4; ++j) {
        wa1v[j] = __shfl(acc1, q * 4 + j, 64);
        wa2v[j] = __shfl(acc2, q * 4 + j, 64);
    }

    // ---- s_item = item[n] . wa1 (each 16-lane group covers all of D) ----
    float s_item = itv[0] * wa1v[0] + itv[1] * wa1v[1] + itv[2] * wa1v[2] + itv[3] * wa1v[3];
    s_item += __shfl_xor(s_item, 1, 64);
    s_item += __shfl_xor(s_item, 2, 64);
    s_item += __shfl_xor(s_item, 4, 64);
    s_item += __shfl_xor(s_item, 8, 64);

    // ---- e[m] = ent[n,m,:] . wa2 ; scatter to LDS (lane m reads back) ----
#pragma unroll
    for (int i = 0; i < 10; ++i) {
        float p = v[i][0] * wa2v[0] + v[i][1] * wa2v[1]
                + v[i][2] * wa2v[2] + v[i][3] * wa2v[3];
        p += __shfl_xor(p, 1, 64);
        p += __shfl_xor(p, 2, 64);
        p += __shfl_xor(p, 4, 64);
        p += __shfl_xor(p, 8, 64);
        if (q == 0) my_e[i * 4 + grp] = p;   // m = i*4 + grp
    }

    // ---- softmax over m (lane m holds e[m]); lanes >= M contribute 0 ----
    float ev;
    if (lane < M) {
        float e = s_item + my_e[lane];
        e = (e > 0.f) ? e : ALPHA_F * e;      // leaky relu
        ev = (am > 0) ? e : NEG_INF_F;        // adjacency mask
    } else {
        ev = -INFINITY;
    }
    float mx = ev;
#pragma unroll
    for (int off = 32; off; off >>= 1) mx = fmaxf(mx, __shfl_xor(mx, off, 64));
    const float ex = __expf(ev - mx);
    float sum = ex;
#pragma unroll
    for (int off = 32; off; off >>= 1) sum += __shfl_xor(sum, off, 64);
    const float wgt = ex / sum;               // lane m: attention[n,m]

    // ---- agg[d] = sum_m w[m] * ent[n,m,d], from registers ----
    f32x4 acc = {0.f, 0.f, 0.f, 0.f};
#pragma unroll
    for (int i = 0; i < 10; ++i) {
        const float w = __shfl(wgt, i * 4 + grp, 64);   // m = i*4+grp < 40
        acc[0] += w * v[i][0];
        acc[1] += w * v[i][1];
        acc[2] += w * v[i][2];
        acc[3] += w * v[i][3];
    }
    // reduce across the 4 groups (lanes q, q+16, q+32, q+48)
#pragma unroll
    for (int off = 16; off <= 32; off <<= 1) {
        acc[0] += __shfl_xor(acc[0], off, 64);
        acc[1] += __shfl_xor(acc[1], off, 64);
        acc[2] += __shfl_xor(acc[2], off, 64);
        acc[3] += __shfl_xor(acc[3], off, 64);
    }
    if (valid && grp == 0) {
        f32x4 o = {acc[0] + itv[0], acc[1] + itv[1],
                   acc[2] + itv[2], acc[3] + itv[3]};
        __builtin_nontemporal_store(
            o, reinterpret_cast<f32x4*>(out + (size_t)n * D + q * 4));
    }
}

// ---------------------------------------------------------------------------
extern "C" void kernel_launch(void* const* d_in, const int* in_sizes, int n_in,
                              void* d_out, int out_size, void* d_ws, size_t ws_size,
                              hipStream_t stream) {
    const float* item = (const float*)d_in[0];   // (N, 64)
    const float* ent  = (const float*)d_in[1];   // (N, 40, 64)
    const int*   adj  = (const int*)d_in[2];     // (N, 40)
    const float* W    = (const float*)d_in[3];   // (64, 64)
    const float* a    = (const float*)d_in[4];   // (128, 1)
    float* out = (float*)d_out;

    const int N = in_sizes[0] / D;
    const int blocks = (N + 3) / 4;
    kgat_fused<<<blocks, 256, 0, stream>>>(item, ent, adj, W, a, out, N);
}

// Round 6
// 59.422 us; speedup vs baseline: 1.4573x; 1.4573x over previous
//
#include <hip/hip_runtime.h>
#include <math.h>

#define NEG_INF_F (-9000000000000000.0f)
#define ALPHA_F 0.2f

static constexpr int D = 64;
static constexpr int M = 40;

using f32x4 = __attribute__((ext_vector_type(4))) float;

// ---------------------------------------------------------------------------
// Pre-kernel: 128 threads, one output each.
// t<64:  wa1[t] = W[t,:] . a[0:64]
// t>=64: wa2[t-64] = W[t-64,:] . a[64:128]
// ---------------------------------------------------------------------------
__global__ void precompute_wa(const float* __restrict__ W,
                              const float* __restrict__ a,
                              float* __restrict__ ws) {
    const int t = threadIdx.x;        // 0..127
    const int d = t & 63;
    const float* wrow = W + d * D;
    const float* av   = a + (t >> 6) * D;
    float acc = 0.f;
#pragma unroll
    for (int e = 0; e < D; e += 4) {
        const f32x4 wv  = *reinterpret_cast<const f32x4*>(wrow + e);
        const f32x4 avv = *reinterpret_cast<const f32x4*>(av + e);
        acc += wv[0] * avv[0] + wv[1] * avv[1] + wv[2] * avv[2] + wv[3] * avv[3];
    }
    ws[t] = acc;
}

// ---------------------------------------------------------------------------
// Main kernel: one wave per row n; entity row in registers (10x f32x4, nt).
// Aux loads (wa, item, adj) are issued BEFORE the entity stream: vmcnt
// retires in order, so s_item runs at vmcnt(10) and each e[m] dot at
// graduated vmcnt — VALU overlaps the in-flight entity loads.
// Lane layout: q = lane&15 (d-chunk q*4..q*4+3), grp = lane>>4.
// v[i] holds ent[n, m = i*4+grp, d = q*4 .. q*4+3].
// ---------------------------------------------------------------------------
__launch_bounds__(256)
__global__ void kgat_kernel(const float* __restrict__ item,
                            const float* __restrict__ ent,
                            const int* __restrict__ adj,
                            const float* __restrict__ wa,   // wa1[64], wa2[64]
                            float* __restrict__ out,
                            int N) {
    __shared__ float lds_e[4][M];   // 160 B per wave: e[m] scatter buffer

    const int wave = threadIdx.x >> 6;
    const int lane = threadIdx.x & 63;
    const int n = blockIdx.x * 4 + wave;
    if (n >= N) return;

    float* my_e = lds_e[wave];
    const int q   = lane & 15;
    const int grp = lane >> 4;

    const float* row = ent + (size_t)n * (M * D);

    // ---- aux loads first (retire early in the in-order vmcnt queue) ----
    const f32x4 wa1v = *reinterpret_cast<const f32x4*>(wa + q * 4);
    const f32x4 wa2v = *reinterpret_cast<const f32x4*>(wa + D + q * 4);
    const f32x4 itv  = __builtin_nontemporal_load(
                           reinterpret_cast<const f32x4*>(item + (size_t)n * D + q * 4));
    const int   am   = (lane < M)
                         ? __builtin_nontemporal_load(adj + (size_t)n * M + lane)
                         : 0;

    // ---- entity stream (nontemporal: read-once) ----
    f32x4 v[10];
#pragma unroll
    for (int i = 0; i < 10; ++i)
        v[i] = __builtin_nontemporal_load(
                   reinterpret_cast<const f32x4*>(row + i * 256 + lane * 4));

    // ---- s_item = item[n] . wa1 (runs while entity loads are in flight) ----
    float s_item = itv[0] * wa1v[0] + itv[1] * wa1v[1] + itv[2] * wa1v[2] + itv[3] * wa1v[3];
    s_item += __shfl_xor(s_item, 1, 64);
    s_item += __shfl_xor(s_item, 2, 64);
    s_item += __shfl_xor(s_item, 4, 64);
    s_item += __shfl_xor(s_item, 8, 64);

    // ---- e[m] = ent[n,m,:] . wa2 ; graduated vmcnt per iteration ----
#pragma unroll
    for (int i = 0; i < 10; ++i) {
        float p = v[i][0] * wa2v[0] + v[i][1] * wa2v[1]
                + v[i][2] * wa2v[2] + v[i][3] * wa2v[3];
        p += __shfl_xor(p, 1, 64);
        p += __shfl_xor(p, 2, 64);
        p += __shfl_xor(p, 4, 64);
        p += __shfl_xor(p, 8, 64);
        if (q == 0) my_e[i * 4 + grp] = p;   // m = i*4 + grp
    }

    // ---- softmax over m (lane m holds e[m]); lanes >= M contribute 0 ----
    float ev;
    if (lane < M) {
        float e = s_item + my_e[lane];
        e = (e > 0.f) ? e : ALPHA_F * e;      // leaky relu
        ev = (am > 0) ? e : NEG_INF_F;        // adjacency mask
    } else {
        ev = -INFINITY;
    }
    float mx = ev;
#pragma unroll
    for (int off = 32; off; off >>= 1) mx = fmaxf(mx, __shfl_xor(mx, off, 64));
    const float ex = __expf(ev - mx);
    float sum = ex;
#pragma unroll
    for (int off = 32; off; off >>= 1) sum += __shfl_xor(sum, off, 64);
    const float wgt = ex / sum;               // lane m: attention[n,m]

    // ---- agg[d] = sum_m w[m] * ent[n,m,d], from registers ----
    f32x4 acc = {0.f, 0.f, 0.f, 0.f};
#pragma unroll
    for (int i = 0; i < 10; ++i) {
        const float w = __shfl(wgt, i * 4 + grp, 64);   // m = i*4+grp < 40
        acc[0] += w * v[i][0];
        acc[1] += w * v[i][1];
        acc[2] += w * v[i][2];
        acc[3] += w * v[i][3];
    }
    // reduce across the 4 groups (lanes q, q+16, q+32, q+48)
#pragma unroll
    for (int off = 16; off <= 32; off <<= 1) {
        acc[0] += __shfl_xor(acc[0], off, 64);
        acc[1] += __shfl_xor(acc[1], off, 64);
        acc[2] += __shfl_xor(acc[2], off, 64);
        acc[3] += __shfl_xor(acc[3], off, 64);
    }
    if (grp == 0) {
        f32x4 o = {acc[0] + itv[0], acc[1] + itv[1],
                   acc[2] + itv[2], acc[3] + itv[3]};
        __builtin_nontemporal_store(
            o, reinterpret_cast<f32x4*>(out + (size_t)n * D + q * 4));
    }
}

// ---------------------------------------------------------------------------
extern "C" void kernel_launch(void* const* d_in, const int* in_sizes, int n_in,
                              void* d_out, int out_size, void* d_ws, size_t ws_size,
                              hipStream_t stream) {
    const float* item = (const float*)d_in[0];   // (N, 64)
    const float* ent  = (const float*)d_in[1];   // (N, 40, 64)
    const int*   adj  = (const int*)d_in[2];     // (N, 40)
    const float* W    = (const float*)d_in[3];   // (64, 64)
    const float* a    = (const float*)d_in[4];   // (128, 1)
    float* out = (float*)d_out;
    float* ws  = (float*)d_ws;                   // 128 floats used

    const int N = in_sizes[0] / D;

    precompute_wa<<<1, 128, 0, stream>>>(W, a, ws);

    const int blocks = (N + 3) / 4;
    kgat_kernel<<<blocks, 256, 0, stream>>>(item, ent, adj, ws, out, N);
}